// Round 10
// baseline (102.675 us; speedup 1.0000x reference)
//
#include <hip/hip_runtime.h>

#define SEQ   3456
#define DH    32
#define FPT   216
#define NT    16
#define IMG0  20
// SCALE * log2(e): QK^T lands in log2 domain; exp2f == v_exp_f32
#define SCALE2 0.2550707067f

#define KPAD   40    // Ks row stride (u16): 80 B (2-way bank alias: free)
#define VPAD   168   // Vt small row stride (u16): 336 B
#define IPAD   232   // Vt img row stride (u16): 464 B
#define PPITCH 40    // P row stride (u16): 80 B

typedef __attribute__((ext_vector_type(8))) short bf16x8;
typedef __attribute__((ext_vector_type(4))) float f32x4;

#define MFMA16(a,b,c) __builtin_amdgcn_mfma_f32_16x16x32_bf16(a,b,c,0,0,0)

__device__ __forceinline__ unsigned short bfh(float f) {      // fp32->bf16 RTNE
    unsigned u = __float_as_uint(f);
    u += 0x7FFFu + ((u >> 16) & 1u);
    return (unsigned short)(u >> 16);
}
__device__ __forceinline__ float bff(unsigned short h) {
    return __uint_as_float((unsigned)h << 16);
}
__device__ __forceinline__ void split8(const float* f, bf16x8& hi, bf16x8& lo) {
    #pragma unroll
    for (int j = 0; j < 8; ++j) {
        unsigned short h = bfh(f[j]);
        hi[j] = (short)h;
        lo[j] = (short)bfh(f[j] - bff(h));
    }
}

// 32-bit key-visibility windows over the 160 small keys (g = d*20+jj),
// verified rounds 7-9. Truncated at nkeys at runtime.
__constant__ unsigned MN_TAB[5] = {0xFEFFFFFFu, 0xFFFFEFFFu, 0xFFEFFFFEu,
                                   0xEFFFFEFFu, 0xFFFEFFFFu};
__constant__ unsigned MJ_TAB[5] = {0x00FFFFFFu, 0xF0000F00u, 0x000F0000u,
                                   0x0F0000F0u, 0x0000F000u};

// Layouts (m89/m118/m120-verified):
//  A-frag 16x16x32: A[m = lane&15][k = (lane>>4)*8 + j]
//  B-frag:          B[k = (lane>>4)*8 + j][n = lane&15]
//  C/D:             D[row = (lane>>4)*4 + reg][col = lane&15]
// Numerics: QK = qhi*khi + qlo*khi; PV/l hi-only (P rounding cancels in ratio).
// Design rules (r7/r8): never add chip-wide work for balance.
// r9 lesson: issue-count cuts don't move the wall -> latency-chain bound;
// this round interleaves 2 independent unit streams per wave for ILP.
__global__ __launch_bounds__(256, 3)
void eye_attn_mfma7(const float* __restrict__ q, const float* __restrict__ k,
                    const float* __restrict__ v, float* __restrict__ out) {
    __shared__ __align__(16) unsigned short KsHi[160 * KPAD];    // 12.8 KB
    __shared__ __align__(16) unsigned short VtHi[DH * VPAD];     // 10.5 KB
    __shared__ __align__(16) unsigned short VtImg[DH * IPAD];    // 14.9 KB
    __shared__ __align__(16) unsigned short Pu[8 * 16 * PPITCH]; // 10.0 KB

    const int t = blockIdx.x, bh = blockIdx.y, half = blockIdx.z;
    const int tid = threadIdx.x;
    const size_t base = (size_t)bh * SEQ * DH;
    const int dmax = (t < 7) ? t : 7;
    const int nkeys = IMG0 * (dmax + 1);
    const int nkt = (nkeys + 31) >> 5;

    const int wv = tid >> 6, lane = tid & 63;
    const int col = lane & 15, quad = lane >> 4;

    // tile plan: half0 w0:{0+img} w1:{1+img} w2:{2,3} w3:{4,5}
    //            half1 w0:{6,7} w1:{8,9} w2:{10,11} w3:{12,13}
    int tA, tB = 0; bool do_img = false;
    if (half == 0) {
        if (wv < 2) { tA = wv; do_img = true; }
        else        { tA = (wv - 2) * 2 + 2; tB = tA + 1; }
    } else {
        tA = 6 + 2 * wv; tB = tA + 1;
    }
    const int mbA = tA * 16, mbB = tB * 16;

    // ---- preload Q raw (latency overlaps staging + barrier) ----
    const float* qpA = q + base + (size_t)(t * FPT + min(mbA + col, FPT - 1)) * DH + quad * 8;
    const float4 qA0 = ((const float4*)qpA)[0];
    const float4 qA1 = ((const float4*)qpA)[1];
    float4 qB0 = qA0, qB1 = qA1;
    if (!do_img) {
        const float* qpB = q + base + (size_t)(t * FPT + min(mbB + col, FPT - 1)) * DH + quad * 8;
        qB0 = ((const float4*)qpB)[0];
        qB1 = ((const float4*)qpB)[1];
    }

    // ---- stage small K rows + small V^T: only the nkeys live rows ----
    for (int i = tid; i < nkeys * 8; i += 256) {
        const int g = i >> 3, c = i & 7;
        const int d = g / IMG0, jj = g - d * IMG0;
        const size_t row = base + (size_t)((t - d) * FPT + jj) * DH + c * 4;
        const float4 kk = *(const float4*)(k + row);
        const float4 vv = *(const float4*)(v + row);
        const float kf[4] = {kk.x, kk.y, kk.z, kk.w};
        const float vf[4] = {vv.x, vv.y, vv.z, vv.w};
        ushort4 khi;
        unsigned short* ah = (unsigned short*)&khi;
        #pragma unroll
        for (int e = 0; e < 4; ++e) ah[e] = bfh(kf[e]);
        *(ushort4*)(KsHi + g * KPAD + c * 4) = khi;
        #pragma unroll
        for (int e = 0; e < 4; ++e)
            VtHi[(c * 4 + e) * VPAD + g] = bfh(vf[e]);
    }
    // zero V^T tail cols [nkeys, nkt*32): 0 * garbage(NaN) would poison PV
    {
        const int rem = nkeys - (nkt - 1) * 32;
        if (rem < 32) {
            for (int i = tid; i < 1024; i += 256) {
                const int c = i & 31;
                if (c >= rem)
                    VtHi[(i >> 5) * VPAD + (nkt - 1) * 32 + c] = 0;
            }
        }
    }
    // img V^T (224 cols, zero-padded past 196): half-0 WGs only
    if (half == 0) {
        for (int i = tid; i < 1792; i += 256) {
            const int gi = i >> 3, c = i & 7;
            float4 vv = make_float4(0.f, 0.f, 0.f, 0.f);
            if (gi < 196) {
                const size_t row = base + (size_t)(t * FPT + IMG0 + gi) * DH + c * 4;
                vv = *(const float4*)(v + row);
            }
            const float vf[4] = {vv.x, vv.y, vv.z, vv.w};
            #pragma unroll
            for (int e = 0; e < 4; ++e)
                VtImg[(c * 4 + e) * IPAD + gi] = bfh(vf[e]);
        }
    }
    __syncthreads();   // only barrier; Pu buffers are wave-private below

    // runtime-truncated small-key visibility masks (wave-uniform)
    unsigned mNt[5], mJt[5];
    #pragma unroll
    for (int kt = 0; kt < 5; ++kt) {
        const int tr = nkeys - kt * 32;
        unsigned mn = MN_TAB[kt], mj = MJ_TAB[kt];
        if (tr <= 0) { mn = 0u; mj = 0u; }
        else if (tr < 32) { const unsigned lim = (1u << tr) - 1u; mn &= lim; mj &= lim; }
        mNt[kt] = mn; mJt[kt] = mj;
    }

    bf16x8 bones;   // B[k][0] = 1: row-sum via MFMA -> l lands in col 0
    #pragma unroll
    for (int j = 0; j < 8; ++j) bones[j] = (short)(col == 0 ? 0x3F80 : 0);

    unsigned short* PA = Pu + (wv * 2 + 0) * 16 * PPITCH;
    unsigned short* PB = Pu + (wv * 2 + 1) * 16 * PPITCH;

    // convert Q fragments (log2-domain scale folded in)
    bf16x8 qAhi, qAlo, qBhi, qBlo;
    {
        float qf[8];
        qf[0]=qA0.x*SCALE2; qf[1]=qA0.y*SCALE2; qf[2]=qA0.z*SCALE2; qf[3]=qA0.w*SCALE2;
        qf[4]=qA1.x*SCALE2; qf[5]=qA1.y*SCALE2; qf[6]=qA1.z*SCALE2; qf[7]=qA1.w*SCALE2;
        split8(qf, qAhi, qAlo);
    }
    if (!do_img) {
        float qf[8];
        qf[0]=qB0.x*SCALE2; qf[1]=qB0.y*SCALE2; qf[2]=qB0.z*SCALE2; qf[3]=qB0.w*SCALE2;
        qf[4]=qB1.x*SCALE2; qf[5]=qB1.y*SCALE2; qf[6]=qB1.z*SCALE2; qf[7]=qB1.w*SCALE2;
        split8(qf, qBhi, qBlo);
    }

    if (!do_img) {
        // ======== two tiles interleaved: shared K/V frags, 2x ILP ========
        f32x4 aO0={0.f,0.f,0.f,0.f}, aO1={0.f,0.f,0.f,0.f}, aL={0.f,0.f,0.f,0.f};
        f32x4 bO0={0.f,0.f,0.f,0.f}, bO1={0.f,0.f,0.f,0.f}, bL={0.f,0.f,0.f,0.f};
        for (int kt = 0; kt < nkt; ++kt) {
            f32x4 sA[2], sB[2];
            #pragma unroll
            for (int h = 0; h < 2; ++h) {
                const int key = kt * 32 + h * 16 + col;
                const bf16x8 khi = *(const bf16x8*)(KsHi + key * KPAD + quad * 8);
                f32x4 x = {0.f,0.f,0.f,0.f};
                x = MFMA16(qAhi, khi, x);
                x = MFMA16(qAlo, khi, x);
                sA[h] = x;
                f32x4 y = {0.f,0.f,0.f,0.f};
                y = MFMA16(qBhi, khi, y);
                y = MFMA16(qBlo, khi, y);
                sB[h] = y;
            }
            #pragma unroll
            for (int r = 0; r < 4; ++r) {
                const int qmA = mbA + quad * 4 + r;
                const int qmB = mbB + quad * 4 + r;
                const bool jA = (qmA >= 4) && (qmA < IMG0);
                const bool jB = (qmB >= 4) && (qmB < IMG0);
                const unsigned mA = (qmA < FPT) ? (jA ? mJt[kt] : mNt[kt]) : 0u;
                const unsigned mB = (qmB < FPT) ? (jB ? mJt[kt] : mNt[kt]) : 0u;
                #pragma unroll
                for (int h = 0; h < 2; ++h) {
                    const int bit = h * 16 + col;
                    const float eA = ((mA >> bit) & 1u) ? exp2f(sA[h][r]) : 0.f;
                    const float eB = ((mB >> bit) & 1u) ? exp2f(sB[h][r]) : 0.f;
                    PA[(quad * 4 + r) * PPITCH + bit] = bfh(eA);
                    PB[(quad * 4 + r) * PPITCH + bit] = bfh(eB);
                }
            }
            const bf16x8 pA = *(const bf16x8*)(PA + col * PPITCH + quad * 8);
            const bf16x8 pB = *(const bf16x8*)(PB + col * PPITCH + quad * 8);
            #pragma unroll
            for (int h = 0; h < 2; ++h) {
                const int dim = h * 16 + col;
                const bf16x8 vhi = *(const bf16x8*)(VtHi + dim * VPAD + kt * 32 + quad * 8);
                if (h == 0) { aO0 = MFMA16(pA, vhi, aO0); bO0 = MFMA16(pB, vhi, bO0); }
                else        { aO1 = MFMA16(pA, vhi, aO1); bO1 = MFMA16(pB, vhi, bO1); }
            }
            aL = MFMA16(pA, bones, aL);
            bL = MFMA16(pB, bones, bL);
        }
        // epilogue A
        #pragma unroll
        for (int r = 0; r < 4; ++r) {
            const float lr = __shfl(aL[r], lane & 48);
            const float inv = 1.f / lr;
            const int qm = mbA + quad * 4 + r;
            if (qm < FPT) {
                float* op = out + base + (size_t)(t * FPT + qm) * DH;
                op[col] = aO0[r] * inv; op[16 + col] = aO1[r] * inv;
            }
        }
        // epilogue B
        #pragma unroll
        for (int r = 0; r < 4; ++r) {
            const float lr = __shfl(bL[r], lane & 48);
            const float inv = 1.f / lr;
            const int qm = mbB + quad * 4 + r;
            if (qm < FPT) {
                float* op = out + base + (size_t)(t * FPT + qm) * DH;
                op[col] = bO0[r] * inv; op[16 + col] = bO1[r] * inv;
            }
        }
    } else {
        // ======== img wave: small stream + img stream interleaved ========
        f32x4 sO0={0.f,0.f,0.f,0.f}, sO1={0.f,0.f,0.f,0.f}, sL={0.f,0.f,0.f,0.f};
        f32x4 iO0={0.f,0.f,0.f,0.f}, iO1={0.f,0.f,0.f,0.f}, iL={0.f,0.f,0.f,0.f};
        for (int it = 0; it < 7; ++it) {
            // issue img K global loads first (latency hides under LDS work)
            float4 ik0[2], ik1[2];
            #pragma unroll
            for (int h = 0; h < 2; ++h) {
                const int keyc = min(IMG0 + it * 32 + h * 16 + col, FPT - 1);
                const float* kp = k + base + (size_t)(t * FPT + keyc) * DH + quad * 8;
                ik0[h] = ((const float4*)kp)[0];
                ik1[h] = ((const float4*)kp)[1];
            }
            const bool doS = it < nkt;
            f32x4 sS[2], sI[2];
            if (doS) {
                #pragma unroll
                for (int h = 0; h < 2; ++h) {
                    const int key = it * 32 + h * 16 + col;
                    const bf16x8 khi = *(const bf16x8*)(KsHi + key * KPAD + quad * 8);
                    f32x4 x = {0.f,0.f,0.f,0.f};
                    x = MFMA16(qAhi, khi, x);
                    x = MFMA16(qAlo, khi, x);
                    sS[h] = x;
                }
            }
            #pragma unroll
            for (int h = 0; h < 2; ++h) {
                float kf[8];
                kf[0]=ik0[h].x; kf[1]=ik0[h].y; kf[2]=ik0[h].z; kf[3]=ik0[h].w;
                kf[4]=ik1[h].x; kf[5]=ik1[h].y; kf[6]=ik1[h].z; kf[7]=ik1[h].w;
                bf16x8 khi;
                #pragma unroll
                for (int j = 0; j < 8; ++j) khi[j] = (short)bfh(kf[j]);
                f32x4 x = {0.f,0.f,0.f,0.f};
                x = MFMA16(qAhi, khi, x);
                x = MFMA16(qAlo, khi, x);
                sI[h] = x;
            }
            if (doS) {
                #pragma unroll
                for (int r = 0; r < 4; ++r) {
                    const int qm = mbA + quad * 4 + r;
                    const bool isj = (qm >= 4) && (qm < IMG0);
                    const unsigned m = isj ? mJt[it] : mNt[it];
                    #pragma unroll
                    for (int h = 0; h < 2; ++h) {
                        const int bit = h * 16 + col;
                        const float e = ((m >> bit) & 1u) ? exp2f(sS[h][r]) : 0.f;
                        PA[(quad * 4 + r) * PPITCH + bit] = bfh(e);
                    }
                }
            }
            #pragma unroll
            for (int h = 0; h < 2; ++h) {
                const int key = IMG0 + it * 32 + h * 16 + col;
                #pragma unroll
                for (int r = 0; r < 4; ++r) {
                    const int qm = mbA + quad * 4 + r;
                    const bool vis = (key < FPT) && (qm < IMG0);
                    const float e = vis ? exp2f(sI[h][r]) : 0.f;
                    PB[(quad * 4 + r) * PPITCH + h * 16 + col] = bfh(e);
                }
            }
            if (doS) {
                const bf16x8 pA = *(const bf16x8*)(PA + col * PPITCH + quad * 8);
                #pragma unroll
                for (int h = 0; h < 2; ++h) {
                    const int dim = h * 16 + col;
                    const bf16x8 vhi = *(const bf16x8*)(VtHi + dim * VPAD + it * 32 + quad * 8);
                    if (h == 0) sO0 = MFMA16(pA, vhi, sO0);
                    else        sO1 = MFMA16(pA, vhi, sO1);
                }
                sL = MFMA16(pA, bones, sL);
            }
            const bf16x8 pB = *(const bf16x8*)(PB + col * PPITCH + quad * 8);
            #pragma unroll
            for (int h = 0; h < 2; ++h) {
                const int dim = h * 16 + col;
                const bf16x8 vhi = *(const bf16x8*)(VtImg + dim * IPAD + it * 32 + quad * 8);
                if (h == 0) iO0 = MFMA16(pB, vhi, iO0);
                else        iO1 = MFMA16(pB, vhi, iO1);
            }
            iL = MFMA16(pB, bones, iL);
        }
        // merge streams + epilogue
        const f32x4 o0 = sO0 + iO0, o1 = sO1 + iO1, lt = sL + iL;
        #pragma unroll
        for (int r = 0; r < 4; ++r) {
            const float lr = __shfl(lt[r], lane & 48);
            const float inv = 1.f / lr;
            const int qm = mbA + quad * 4 + r;
            if (qm < FPT) {
                float* op = out + base + (size_t)(t * FPT + qm) * DH;
                op[col] = o0[r] * inv; op[16 + col] = o1[r] * inv;
            }
        }
    }
}

extern "C" void kernel_launch(void* const* d_in, const int* in_sizes, int n_in,
                              void* d_out, int out_size, void* d_ws, size_t ws_size,
                              hipStream_t stream) {
    const float* q = (const float*)d_in[0];
    const float* k = (const float*)d_in[1];
    const float* v = (const float*)d_in[2];
    float* out = (float*)d_out;
    const int BH = in_sizes[0] / (SEQ * DH);   // 24
    dim3 grid(NT, BH, 2);                      // 768 WGs = 3/CU even
    eye_attn_mfma7<<<grid, 256, 0, stream>>>(q, k, v, out);
}

// Round 11
// 98.284 us; speedup vs baseline: 1.0447x; 1.0447x over previous
//
#include <hip/hip_runtime.h>

#define SEQ   3456
#define DH    32
#define FPT   216
#define NT    16
#define IMG0  20
#define SCALE 0.17677669529663687f

#define KPAD   40    // Ks row stride (u16): 80 B -> 2-way bank alias (free)
#define VPAD   168   // Vt row stride (u16): 336 B
#define PPITCH 40    // P row stride (u16): 80 B

typedef __attribute__((ext_vector_type(8))) short bf16x8;
typedef __attribute__((ext_vector_type(4))) float f32x4;

#define MFMA16(a,b,c) __builtin_amdgcn_mfma_f32_16x16x32_bf16(a,b,c,0,0,0)

__device__ __forceinline__ unsigned short bfh(float f) {      // fp32->bf16 RTNE
    unsigned u = __float_as_uint(f);
    u += 0x7FFFu + ((u >> 16) & 1u);
    return (unsigned short)(u >> 16);
}
__device__ __forceinline__ float bff(unsigned short h) {
    return __uint_as_float((unsigned)h << 16);
}
__device__ __forceinline__ void split8(const float* f, bf16x8& hi, bf16x8& lo) {
    #pragma unroll
    for (int j = 0; j < 8; ++j) {
        unsigned short h = bfh(f[j]);
        hi[j] = (short)h;
        lo[j] = (short)bfh(f[j] - bff(h));
    }
}

// Round-6 kernel (best measured: 97.2 us total, absmax 0.0078).
// Rounds 7-10 (forced unroll, rebalance+img-LDS, strict work cuts, 2-stream
// ILP) all landed 99-103 -> the kernel is latency-bound at ~25-30 us with
// every pipe <10% utilized; structural rewrites don't move it. Locked in.
//
// Layouts (m89/m118/m120-verified):
//  A-frag 16x16x32: A[m = lane&15][k = (lane>>4)*8 + j]
//  B-frag:          B[k = (lane>>4)*8 + j][n = lane&15]
//  C/D:             D[row = (lane>>4)*4 + reg][col = lane&15]
// Accuracy: QK = (qhi+qlo)*khi (k_lo dropped: ~1e-3 score noise).
// PV/l hi-only: P rounding cancels in softmax ratio; V rounding ~0.4% rel.
__global__ __launch_bounds__(256)
void eye_attn_mfma2(const float* __restrict__ q, const float* __restrict__ k,
                    const float* __restrict__ v, float* __restrict__ out) {
    __shared__ __align__(16) unsigned short KsHi[160 * KPAD];   // 12.8 KB
    __shared__ __align__(16) unsigned short KsLo[160 * KPAD];   // 12.8 KB
    __shared__ __align__(16) unsigned short VtHi[DH * VPAD];    // 10.75 KB
    __shared__ __align__(16) unsigned short Pu[4 * 16 * PPITCH];// 5.1 KB

    const int t = blockIdx.x, bh = blockIdx.y, half = blockIdx.z;
    const int tid = threadIdx.x;
    const size_t base = (size_t)bh * SEQ * DH;
    const int dmax = (t < 7) ? t : 7;
    const int nkeys = IMG0 * (dmax + 1);     // staged small keys (g = d*20+jj)

    // ---- stage small K (hi/lo rows) and V^T (hi only), zero-padded ----
    for (int i = tid; i < 160 * 8; i += 256) {
        const int g = i >> 3, c = i & 7;
        float4 kk = make_float4(0.f,0.f,0.f,0.f), vv = make_float4(0.f,0.f,0.f,0.f);
        if (g < nkeys) {
            const int d = g / IMG0, jj = g - d * IMG0;
            const size_t row = base + (size_t)((t - d) * FPT + jj) * DH + c * 4;
            kk = *(const float4*)(k + row);
            vv = *(const float4*)(v + row);
        }
        const float kf[4] = {kk.x, kk.y, kk.z, kk.w};
        const float vf[4] = {vv.x, vv.y, vv.z, vv.w};
        ushort4 khi, klo;
        unsigned short* ah = (unsigned short*)&khi;
        unsigned short* al = (unsigned short*)&klo;
        #pragma unroll
        for (int e = 0; e < 4; ++e) {
            const unsigned short h = bfh(kf[e]);
            ah[e] = h;
            al[e] = bfh(kf[e] - bff(h));
        }
        *(ushort4*)(KsHi + g * KPAD + c * 4) = khi;
        *(ushort4*)(KsLo + g * KPAD + c * 4) = klo;
        #pragma unroll
        for (int e = 0; e < 4; ++e)
            VtHi[(c * 4 + e) * VPAD + g] = bfh(vf[e]);
    }
    __syncthreads();   // only barrier; Pu regions are wave-private below

    const int wv = tid >> 6, lane = tid & 63;
    const int col = lane & 15, quad = lane >> 4;

    // 14 M-tiles over 2 WGs x 4 waves; img work (tiles 0,1) on half0 w0/w1
    int mt[2]; int mcnt; bool do_img = false;
    if (half == 0) {
        if (wv == 0)      { mt[0] = 0; mcnt = 1; do_img = true; }
        else if (wv == 1) { mt[0] = 1; mcnt = 1; do_img = true; }
        else if (wv == 2) { mt[0] = 2; mt[1] = 3; mcnt = 2; }
        else              { mt[0] = 4; mt[1] = 5; mcnt = 2; }
    } else {
        mt[0] = 6 + 2 * wv; mt[1] = 7 + 2 * wv; mcnt = 2;
    }

    bf16x8 bones;   // B[k][0] = 1: row-sum via MFMA -> l lands in col 0
    #pragma unroll
    for (int j = 0; j < 8; ++j) bones[j] = (short)(col == 0 ? 0x3F80 : 0);

    unsigned short* myP = Pu + wv * 16 * PPITCH;
    const int nkt = (nkeys + 31) >> 5;

    for (int mi = 0; mi < mcnt; ++mi) {
        const int mb = mt[mi] * 16;
        bf16x8 qhi, qlo;
        {
            const int qc = min(mb + col, FPT - 1);   // clamp; masked on store
            const float* qp = q + base + (size_t)(t * FPT + qc) * DH + quad * 8;
            float qf[8];
            const float4 a0 = *(const float4*)qp;
            const float4 a1 = *(const float4*)(qp + 4);
            qf[0]=a0.x*SCALE; qf[1]=a0.y*SCALE; qf[2]=a0.z*SCALE; qf[3]=a0.w*SCALE;
            qf[4]=a1.x*SCALE; qf[5]=a1.y*SCALE; qf[6]=a1.z*SCALE; qf[7]=a1.w*SCALE;
            split8(qf, qhi, qlo);
        }
        f32x4 oacc0 = {0.f,0.f,0.f,0.f}, oacc1 = {0.f,0.f,0.f,0.f};
        f32x4 lacc = {0.f,0.f,0.f,0.f};

        // ---- small keys: QK^T -> mask/exp -> P(bf16) roundtrip -> PV + l ----
        for (int kt = 0; kt < nkt; ++kt) {
            f32x4 s[2];
            #pragma unroll
            for (int h = 0; h < 2; ++h) {
                const int key = kt * 32 + h * 16 + col;
                const bf16x8 khi = *(const bf16x8*)(KsHi + key * KPAD + quad * 8);
                const bf16x8 klo = *(const bf16x8*)(KsLo + key * KPAD + quad * 8);
                f32x4 acc = {0.f,0.f,0.f,0.f};
                acc = MFMA16(qhi, khi, acc);
                acc = MFMA16(qlo, khi, acc);
                acc = MFMA16(qhi, klo, acc);
                s[h] = acc;
            }
            #pragma unroll
            for (int h = 0; h < 2; ++h) {
                const int g = kt * 32 + h * 16 + col;
                const int d = g / IMG0, jj = g - d * IMG0;
                #pragma unroll
                for (int r = 0; r < 4; ++r) {
                    const int qm = mb + quad * 4 + r;
                    const bool qj = (qm >= 4) && (qm < IMG0);
                    const bool vis = (g < nkeys) && (qm < FPT) &&
                                     ((d == 0) || ((jj != 4) && !(qj && jj >= 4)));
                    const float e = vis ? __expf(s[h][r]) : 0.f;
                    myP[(quad * 4 + r) * PPITCH + h * 16 + col] = bfh(e);
                }
            }
            const bf16x8 phi = *(const bf16x8*)(myP + col * PPITCH + quad * 8);
            #pragma unroll
            for (int h = 0; h < 2; ++h) {
                const int dim = h * 16 + col;
                const bf16x8 vhi = *(const bf16x8*)(VtHi + dim * VPAD + kt * 32 + quad * 8);
                f32x4& oa = h ? oacc1 : oacc0;
                oa = MFMA16(phi, vhi, oa);
            }
            lacc = MFMA16(phi, bones, lacc);
        }

        // ---- same-t img keys (20..215): only queries qm<20 (tiles 0,1) ----
        if (mi == 0 && do_img) {
            for (int kt2 = 0; kt2 < 7; ++kt2) {
                f32x4 s[2];
                #pragma unroll
                for (int h = 0; h < 2; ++h) {
                    const int keyc = min(IMG0 + kt2 * 32 + h * 16 + col, FPT - 1);
                    const float* kp = k + base + (size_t)(t * FPT + keyc) * DH + quad * 8;
                    float kf[8];
                    const float4 a0 = *(const float4*)kp;
                    const float4 a1 = *(const float4*)(kp + 4);
                    kf[0]=a0.x; kf[1]=a0.y; kf[2]=a0.z; kf[3]=a0.w;
                    kf[4]=a1.x; kf[5]=a1.y; kf[6]=a1.z; kf[7]=a1.w;
                    bf16x8 khi, klo;
                    split8(kf, khi, klo);
                    f32x4 acc = {0.f,0.f,0.f,0.f};
                    acc = MFMA16(qhi, khi, acc);
                    acc = MFMA16(qlo, khi, acc);
                    acc = MFMA16(qhi, klo, acc);
                    s[h] = acc;
                }
                #pragma unroll
                for (int h = 0; h < 2; ++h) {
                    const int key = IMG0 + kt2 * 32 + h * 16 + col;
                    #pragma unroll
                    for (int r = 0; r < 4; ++r) {
                        const int qm = mb + quad * 4 + r;
                        const bool vis = (key < FPT) && (qm < IMG0);
                        const float e = vis ? __expf(s[h][r]) : 0.f;
                        myP[(quad * 4 + r) * PPITCH + h * 16 + col] = bfh(e);
                    }
                }
                const bf16x8 phi = *(const bf16x8*)(myP + col * PPITCH + quad * 8);
                #pragma unroll
                for (int h = 0; h < 2; ++h) {
                    const int dim = h * 16 + col;
                    float vf[8];
                    #pragma unroll
                    for (int j = 0; j < 8; ++j) {
                        const int ky = min(IMG0 + kt2 * 32 + quad * 8 + j, FPT - 1);
                        vf[j] = v[base + (size_t)(t * FPT + ky) * DH + dim];
                    }
                    bf16x8 vhi;
                    #pragma unroll
                    for (int j = 0; j < 8; ++j) vhi[j] = (short)bfh(vf[j]);
                    f32x4& oa = h ? oacc1 : oacc0;
                    oa = MFMA16(phi, vhi, oa);
                }
                lacc = MFMA16(phi, bones, lacc);
            }
        }

        // ---- epilogue: broadcast l (col 0 of quad), normalize, store ----
        #pragma unroll
        for (int r = 0; r < 4; ++r) {
            const float lr = __shfl(lacc[r], lane & 48);   // lane (quad*16 + 0)
            const float inv = 1.f / lr;
            const int qm = mb + quad * 4 + r;
            if (qm < FPT) {
                float* op = out + base + (size_t)(t * FPT + qm) * DH;
                op[col]      = oacc0[r] * inv;
                op[16 + col] = oacc1[r] * inv;
            }
        }
    }
}

extern "C" void kernel_launch(void* const* d_in, const int* in_sizes, int n_in,
                              void* d_out, int out_size, void* d_ws, size_t ws_size,
                              hipStream_t stream) {
    const float* q = (const float*)d_in[0];
    const float* k = (const float*)d_in[1];
    const float* v = (const float*)d_in[2];
    float* out = (float*)d_out;
    const int BH = in_sizes[0] / (SEQ * DH);   // 24
    dim3 grid(NT, BH, 2);                      // 768 WGs = 3/CU even
    eye_attn_mfma2<<<grid, 256, 0, stream>>>(q, k, v, out);
}